// Round 3
// baseline (31.919 us; speedup 1.0000x reference)
//
#include <hip/hip_runtime.h>
#include <hip/hip_fp16.h>
#include <math.h>

// DRR ray-caster, round 3.
// Bottleneck model (validated r1/r2): L1 cacheline-lookup throughput.
// Lanes vary along image-u -> volume x (stride 256KB) -> ~34 lines/gather.
// Fix: per-call transpose+f16-convert volume to T[z][y][x] in d_ws; then a
// wave of 32 consecutive-u pixels gathers ~17 CONTIGUOUS f16 -> 2-4 lines.
// f32 inside/index arithmetic is bit-identical to rounds 1-2; only sample
// values carry f16 error (<=0.06 on the image; margin was 2.0).

#define BLOCK  256
#define PPB    32          // pixels per block
#define CHUNKS 8           // step chunks per pixel

// ---------------- transpose + f32->f16: V[x][y][z] -> T[z][y][x] ----------
__global__ __launch_bounds__(256) void transpose_f16_kernel(
    const float* __restrict__ vol, __half* __restrict__ T)
{
    __shared__ float tile[64][65];
    const int t  = (int)threadIdx.x;
    const int xb = (int)blockIdx.x * 64;
    const int zb = (int)blockIdx.y * 64;
    const int y  = (int)blockIdx.z;

    const int zq = (t & 15) * 4;
    const int xr = t >> 4;
    #pragma unroll
    for (int i = 0; i < 4; ++i) {
        const int xl = xr + 16 * i;
        const float4 v = *reinterpret_cast<const float4*>(
            vol + ((size_t)(xb + xl) << 16) + ((size_t)y << 8) + (zb + zq));
        tile[xl][zq + 0] = v.x;
        tile[xl][zq + 1] = v.y;
        tile[xl][zq + 2] = v.z;
        tile[xl][zq + 3] = v.w;
    }
    __syncthreads();

    const int xq = (t & 15) * 4;
    const int zr = t >> 4;
    #pragma unroll
    for (int i = 0; i < 4; ++i) {
        const int zl = zr + 16 * i;
        const __half2 lo = __floats2half2_rn(tile[xq + 0][zl], tile[xq + 1][zl]);
        const __half2 hi = __floats2half2_rn(tile[xq + 2][zl], tile[xq + 3][zl]);
        uint2 pk;
        pk.x = *reinterpret_cast<const unsigned int*>(&lo);
        pk.y = *reinterpret_cast<const unsigned int*>(&hi);
        *reinterpret_cast<uint2*>(
            T + ((size_t)(zb + zl) << 16) + ((size_t)y << 8) + (xb + xq)) = pk;
    }
}

// ---------------- main ray-cast kernel, f16 transposed volume (D=256) -----
__global__ __launch_bounds__(BLOCK) void drr_f16_kernel(
    const __half* __restrict__ T,
    const float* __restrict__ rt_inv,
    const float* __restrict__ k_inv,
    const float* __restrict__ sdd_p,
    const float* __restrict__ rot_p,
    const float* __restrict__ xyz_p,
    const int*   __restrict__ width_p,
    const int*   __restrict__ nsteps_p,
    float*       __restrict__ out,
    const int npix)
{
    const float dimf = 255.0f;

    __shared__ float s_rayx[PPB], s_rayy[PPB], s_rayz[PPB], s_seglen[PPB];
    __shared__ int   s_ilo[PPB], s_ihi[PPB];
    __shared__ float s_q[3];
    __shared__ float s_red[BLOCK];

    const int   tid = (int)threadIdx.x;
    const int   n   = nsteps_p[0];
    const float fn  = (float)n;

    if (tid < PPB) {
        const int p = (int)blockIdx.x * PPB + tid;

        const float rx = rot_p[0], ry = rot_p[1], rz = rot_p[2];
        const float th2 = rx*rx + ry*ry + rz*rz;
        const float th  = sqrtf(th2 + 1e-30f);
        const float a   = (th2 < 1e-12f) ? (1.0f - th2 * (1.0f/6.0f))  : (sinf(th) / th);
        const float b   = (th2 < 1e-12f) ? (0.5f - th2 * (1.0f/24.0f)) : ((1.0f - cosf(th)) / th2);
        float Rm[3][3];
        Rm[0][0] = 1.0f + b * (-(ry*ry + rz*rz));
        Rm[0][1] = a * (-rz) + b * (rx*ry);
        Rm[0][2] = a * ( ry) + b * (rx*rz);
        Rm[1][0] = a * ( rz) + b * (rx*ry);
        Rm[1][1] = 1.0f + b * (-(rx*rx + rz*rz));
        Rm[1][2] = a * (-rx) + b * (ry*rz);
        Rm[2][0] = a * (-ry) + b * (rx*rz);
        Rm[2][1] = a * ( rx) + b * (ry*rz);
        Rm[2][2] = 1.0f + b * (-(rx*rx + ry*ry));
        const float tv[3] = { xyz_p[0], xyz_p[1], xyz_p[2] };
        const float* M = rt_inv;
        float Rw[3][3], tw[3];
        #pragma unroll
        for (int i = 0; i < 3; ++i) {
            #pragma unroll
            for (int j = 0; j < 4; ++j) {
                float s = Rm[i][0]*M[0*4+j] + Rm[i][1]*M[1*4+j]
                        + Rm[i][2]*M[2*4+j] + tv[i]*M[3*4+j];
                if (j < 3) Rw[i][j] = s; else tw[i] = s;
            }
        }
        const float c = 127.5f;
        if (tid == 0) { s_q[0] = tw[0] + c; s_q[1] = tw[1] + c; s_q[2] = tw[2] + c; }

        int   ilo = 0, ihi = -1;
        float rayx = 0.f, rayy = 0.f, rayz = 0.f, seglen = 0.f;
        if (p < npix) {
            const int W = *width_p;
            const int h = p / W;
            const int w = p - h * W;
            const float sdd = sdd_p[0];
            const float u = (float)w + 0.5f;
            const float v = (float)h + 0.5f;
            const float cx = (k_inv[0]*u + k_inv[1]*v + k_inv[2]) * sdd;
            const float cy = (k_inv[3]*u + k_inv[4]*v + k_inv[5]) * sdd;
            const float cz = (k_inv[6]*u + k_inv[7]*v + k_inv[8]) * sdd;
            const float tgx = Rw[0][0]*cx + Rw[0][1]*cy + Rw[0][2]*cz + tw[0];
            const float tgy = Rw[1][0]*cx + Rw[1][1]*cy + Rw[1][2]*cz + tw[1];
            const float tgz = Rw[2][0]*cx + Rw[2][1]*cy + Rw[2][2]*cz + tw[2];
            rayx = tgx - tw[0];
            rayy = tgy - tw[1];
            rayz = tgz - tw[2];
            seglen = sqrtf(rayx*rayx + rayy*rayy + rayz*rayz) / fn;

            const float qs[3] = { tw[0] + c, tw[1] + c, tw[2] + c };
            const float rs[3] = { rayx, rayy, rayz };
            float alo = -1e30f, ahi = 1e30f;
            bool empty = false;
            #pragma unroll
            for (int ax = 0; ax < 3; ++ax) {
                const float q = qs[ax], r = rs[ax];
                if (fabsf(r) < 1e-20f) {
                    if (q < 0.0f || q > dimf) empty = true;
                } else {
                    const float t0 = (0.0f - q) / r;
                    const float t1 = (dimf - q) / r;
                    alo = fmaxf(alo, fminf(t0, t1));
                    ahi = fminf(ahi, fmaxf(t0, t1));
                }
            }
            if (!empty && alo <= ahi) {
                ilo = (int)ceilf (alo * fn - 0.5f) - 1;
                ihi = (int)floorf(ahi * fn - 0.5f) + 1;
                ilo = max(ilo, 0);
                ihi = min(ihi, n - 1);
            }
        }
        s_rayx[tid] = rayx;  s_rayy[tid] = rayy;  s_rayz[tid] = rayz;
        s_seglen[tid] = seglen;
        s_ilo[tid] = ilo;    s_ihi[tid] = ihi;
    }
    __syncthreads();

    const int slot  = tid & (PPB - 1);
    const int chunk = tid >> 5;

    const float rayx = s_rayx[slot], rayy = s_rayy[slot], rayz = s_rayz[slot];
    const float qx = s_q[0], qy = s_q[1], qz = s_q[2];
    const int ilo = s_ilo[slot], ihi = s_ihi[slot];

    float acc = 0.0f;
    const float inv_n = 1.0f / fn;
    const int start = ilo + (((chunk - ilo) % CHUNKS) + CHUNKS) % CHUNKS;

    for (int i = start; i <= ihi; i += CHUNKS) {
        const float alpha = ((float)i + 0.5f) * inv_n;
        const float px = fmaf(alpha, rayx, qx);
        const float py = fmaf(alpha, rayy, qy);
        const float pz = fmaf(alpha, rayz, qz);
        const bool inside = (px >= 0.0f) & (px <= dimf)
                          & (py >= 0.0f) & (py <= dimf)
                          & (pz >= 0.0f) & (pz <= dimf);
        if (!inside) continue;
        const float fxf = floorf(px), fyf = floorf(py), fzf = floorf(pz);
        const float fx = px - fxf, fy = py - fyf, fz = pz - fzf;
        const int x0 = min(max((int)fxf, 0), 254);
        const int y0 = min(max((int)fyf, 0), 254);
        const int z0 = min(max((int)fzf, 0), 254);
        const __half* bp = T + ((z0 << 16) + (y0 << 8) + x0);
        const float c000 = __half2float(bp[0]);
        const float c100 = __half2float(bp[1]);
        const float c010 = __half2float(bp[256]);
        const float c110 = __half2float(bp[257]);
        const float c001 = __half2float(bp[65536]);
        const float c101 = __half2float(bp[65537]);
        const float c011 = __half2float(bp[65792]);
        const float c111 = __half2float(bp[65793]);
        const float c00 = c000 * (1.0f - fz) + c001 * fz;
        const float c01 = c010 * (1.0f - fz) + c011 * fz;
        const float c10 = c100 * (1.0f - fz) + c101 * fz;
        const float c11 = c110 * (1.0f - fz) + c111 * fz;
        const float c0  = c00 * (1.0f - fy) + c01 * fy;
        const float c1  = c10 * (1.0f - fy) + c11 * fy;
        acc += c0 * (1.0f - fx) + c1 * fx;
    }

    s_red[tid] = acc;
    __syncthreads();
    if (tid < PPB) {
        float s = 0.0f;
        #pragma unroll
        for (int k = 0; k < CHUNKS; ++k) s += s_red[tid + k * PPB];
        const int p = (int)blockIdx.x * PPB + tid;
        if (p < npix) out[p] = s * s_seglen[tid];
    }
}

// ---------------- fallback: round-1 f32 direct kernel ---------------------
__global__ __launch_bounds__(BLOCK) void drr_kernel(
    const float* __restrict__ vol,
    const float* __restrict__ rt_inv,
    const float* __restrict__ k_inv,
    const float* __restrict__ sdd_p,
    const float* __restrict__ rot_p,
    const float* __restrict__ xyz_p,
    const int*   __restrict__ width_p,
    const int*   __restrict__ nsteps_p,
    float*       __restrict__ out,
    const int npix, const int D)
{
    const int tid   = (int)threadIdx.x;
    const int slot  = tid & (PPB - 1);
    const int chunk = tid / PPB;
    const int p     = (int)blockIdx.x * PPB + slot;

    float acc    = 0.0f;
    float seglen = 0.0f;

    if (p < npix) {
        const int W = *width_p;
        const int n = *nsteps_p;
        const int h = p / W;
        const int w = p - h * W;

        const float rx = rot_p[0], ry = rot_p[1], rz = rot_p[2];
        const float th2 = rx*rx + ry*ry + rz*rz;
        const float th  = sqrtf(th2 + 1e-30f);
        const float a   = (th2 < 1e-12f) ? (1.0f - th2 * (1.0f/6.0f))  : (sinf(th) / th);
        const float b   = (th2 < 1e-12f) ? (0.5f - th2 * (1.0f/24.0f)) : ((1.0f - cosf(th)) / th2);
        float Rm[3][3];
        Rm[0][0] = 1.0f + b * (-(ry*ry + rz*rz));
        Rm[0][1] = a * (-rz) + b * (rx*ry);
        Rm[0][2] = a * ( ry) + b * (rx*rz);
        Rm[1][0] = a * ( rz) + b * (rx*ry);
        Rm[1][1] = 1.0f + b * (-(rx*rx + rz*rz));
        Rm[1][2] = a * (-rx) + b * (ry*rz);
        Rm[2][0] = a * (-ry) + b * (rx*rz);
        Rm[2][1] = a * ( rx) + b * (ry*rz);
        Rm[2][2] = 1.0f + b * (-(rx*rx + ry*ry));
        const float tv[3] = { xyz_p[0], xyz_p[1], xyz_p[2] };
        const float* M = rt_inv;
        float Rw[3][3], tw[3];
        #pragma unroll
        for (int i = 0; i < 3; ++i) {
            #pragma unroll
            for (int j = 0; j < 4; ++j) {
                float s = Rm[i][0]*M[0*4+j] + Rm[i][1]*M[1*4+j]
                        + Rm[i][2]*M[2*4+j] + tv[i]*M[3*4+j];
                if (j < 3) Rw[i][j] = s; else tw[i] = s;
            }
        }

        const float sdd = sdd_p[0];
        const float u = (float)w + 0.5f;
        const float v = (float)h + 0.5f;
        const float cx = (k_inv[0]*u + k_inv[1]*v + k_inv[2]) * sdd;
        const float cy = (k_inv[3]*u + k_inv[4]*v + k_inv[5]) * sdd;
        const float cz = (k_inv[6]*u + k_inv[7]*v + k_inv[8]) * sdd;
        const float tgx = Rw[0][0]*cx + Rw[0][1]*cy + Rw[0][2]*cz + tw[0];
        const float tgy = Rw[1][0]*cx + Rw[1][1]*cy + Rw[1][2]*cz + tw[1];
        const float tgz = Rw[2][0]*cx + Rw[2][1]*cy + Rw[2][2]*cz + tw[2];
        const float rayx = tgx - tw[0];
        const float rayy = tgy - tw[1];
        const float rayz = tgz - tw[2];
        const float fn = (float)n;
        seglen = sqrtf(rayx*rayx + rayy*rayy + rayz*rayz) / fn;

        const float c    = 0.5f * (float)(D - 1);
        const float dimf = (float)(D - 1);
        const float qx = tw[0] + c, qy = tw[1] + c, qz = tw[2] + c;

        float alo = -1e30f, ahi = 1e30f;
        bool empty = false;
        {
            const float qs[3] = { qx, qy, qz };
            const float rs[3] = { rayx, rayy, rayz };
            #pragma unroll
            for (int ax = 0; ax < 3; ++ax) {
                const float q = qs[ax], r = rs[ax];
                if (fabsf(r) < 1e-20f) {
                    if (q < 0.0f || q > dimf) empty = true;
                } else {
                    const float t0 = (0.0f - q) / r;
                    const float t1 = (dimf - q) / r;
                    alo = fmaxf(alo, fminf(t0, t1));
                    ahi = fminf(ahi, fmaxf(t0, t1));
                }
            }
        }

        if (!empty && alo <= ahi) {
            int ilo = (int)ceilf (alo * fn - 0.5f) - 1;
            int ihi = (int)floorf(ahi * fn - 0.5f) + 1;
            ilo = max(ilo, 0);
            ihi = min(ihi, n - 1);
            int start = ilo + ((chunk - ilo) % CHUNKS + CHUNKS) % CHUNKS;

            const float inv_n = 1.0f / fn;
            const int DD = D * D;
            for (int i = start; i <= ihi; i += CHUNKS) {
                const float alpha = ((float)i + 0.5f) * inv_n;
                const float px = fmaf(alpha, rayx, qx);
                const float py = fmaf(alpha, rayy, qy);
                const float pz = fmaf(alpha, rayz, qz);
                const bool inside = (px >= 0.0f) & (px <= dimf)
                                  & (py >= 0.0f) & (py <= dimf)
                                  & (pz >= 0.0f) & (pz <= dimf);
                if (!inside) continue;
                const float fxf = floorf(px), fyf = floorf(py), fzf = floorf(pz);
                const float fx = px - fxf, fy = py - fyf, fz = pz - fzf;
                int x0 = min(max((int)fxf, 0), D - 2);
                int y0 = min(max((int)fyf, 0), D - 2);
                int z0 = min(max((int)fzf, 0), D - 2);
                const float* b000 = vol + (size_t)x0 * DD + (size_t)y0 * D + z0;
                const float c000 = b000[0];
                const float c001 = b000[1];
                const float c010 = b000[D];
                const float c011 = b000[D + 1];
                const float c100 = b000[DD];
                const float c101 = b000[DD + 1];
                const float c110 = b000[DD + D];
                const float c111 = b000[DD + D + 1];
                const float c00 = c000 * (1.0f - fz) + c001 * fz;
                const float c01 = c010 * (1.0f - fz) + c011 * fz;
                const float c10 = c100 * (1.0f - fz) + c101 * fz;
                const float c11 = c110 * (1.0f - fz) + c111 * fz;
                const float c0  = c00 * (1.0f - fy) + c01 * fy;
                const float c1  = c10 * (1.0f - fy) + c11 * fy;
                acc += c0 * (1.0f - fx) + c1 * fx;
            }
        }
    }

    __shared__ float red[BLOCK];
    red[tid] = acc;
    __syncthreads();
    if (tid < PPB) {
        float s = 0.0f;
        #pragma unroll
        for (int k = 0; k < CHUNKS; ++k) s += red[tid + k * PPB];
        if (p < npix) out[p] = s * seglen;
    }
}

extern "C" void kernel_launch(void* const* d_in, const int* in_sizes, int n_in,
                              void* d_out, int out_size, void* d_ws, size_t ws_size,
                              hipStream_t stream) {
    const float* vol    = (const float*)d_in[0];
    const float* rt_inv = (const float*)d_in[1];
    const float* k_inv  = (const float*)d_in[2];
    const float* sdd    = (const float*)d_in[3];
    const float* rot    = (const float*)d_in[4];
    const float* xyz    = (const float*)d_in[5];
    const int*   width  = (const int*)d_in[7];
    const int*   nsteps = (const int*)d_in[8];
    float* out = (float*)d_out;

    const int npix = out_size;                       // H*W
    const int D    = (int)lround(cbrt((double)in_sizes[0]));

    const size_t need = (size_t)256 * 256 * 256 * sizeof(__half);  // 32 MiB
    const int blocks = (npix + PPB - 1) / PPB;
    if (D == 256 && ws_size >= need) {
        __half* T = (__half*)d_ws;
        dim3 tgrid(4, 4, 256);
        transpose_f16_kernel<<<tgrid, 256, 0, stream>>>(vol, T);
        drr_f16_kernel<<<blocks, BLOCK, 0, stream>>>(
            T, rt_inv, k_inv, sdd, rot, xyz, width, nsteps, out, npix);
    } else {
        drr_kernel<<<blocks, BLOCK, 0, stream>>>(
            vol, rt_inv, k_inv, sdd, rot, xyz, width, nsteps, out, npix, D);
    }
}

// Round 4
// 30.407 us; speedup vs baseline: 1.0497x; 1.0497x over previous
//
#include <hip/hip_runtime.h>
#include <math.h>

// DRR ray-caster, round 4: direct f32 volume (no per-call transpose).
// Bottleneck (validated r1-r3): L1-line lookups / L2 request traffic from
// gathers whose lanes spread across the 256KB-strided x axis.
// Levers this round:
//  - z-pair merged loads (8 -> 4 gather instrs/step, same lines each)
//  - 64-lane same-step waves (no 2-step footprint doubling within a wave)
//  - contiguous per-chunk step ranges (z walks 5 voxels/step -> ~3-step
//    L1 line reuse within a wave)
//  - XCD v-band blockIdx swizzle (each XCD's 4MiB L2 holds its sub-frustum)
// Sample arithmetic is bit-identical to round 1 (passed, absmax 1.0).

#define BLOCK  512
#define PPB    64          // pixels per block (one wave-width of u)
#define CHUNKS 8           // step-chunk waves per block

typedef float f32x2 __attribute__((ext_vector_type(2), aligned(4)));

template <int DC>
__global__ __launch_bounds__(BLOCK) void drr_swz_kernel(
    const float* __restrict__ vol,
    const float* __restrict__ rt_inv,
    const float* __restrict__ k_inv,
    const float* __restrict__ sdd_p,
    const float* __restrict__ rot_p,
    const float* __restrict__ xyz_p,
    const int*   __restrict__ width_p,
    const int*   __restrict__ nsteps_p,
    float*       __restrict__ out,
    const int npix, const int Drt)
{
    const int   D    = (DC > 0) ? DC : Drt;
    const int   DD   = D * D;
    const float dimf = (float)(D - 1);

    __shared__ float s_rayx[PPB], s_rayy[PPB], s_rayz[PPB], s_seglen[PPB];
    __shared__ int   s_ilo[PPB], s_ihi[PPB];
    __shared__ float s_q[3];
    __shared__ float s_red[CHUNKS][PPB];

    const int   tid = (int)threadIdx.x;
    const int   n   = nsteps_p[0];
    const float fn  = (float)n;
    const int   W   = width_p[0];

    // ---- block -> pixel-base mapping (XCD v-band swizzle when 256x256) ----
    const int bi = (int)blockIdx.x;
    int p0;
    if (W == 256 && npix == 65536) {
        const int band   = bi & 7;         // ~XCD id
        const int within = bi >> 3;        // 0..127
        const int vrow   = band * 32 + (within >> 2);
        const int u0     = (within & 3) * 64;
        p0 = vrow * 256 + u0;
    } else {
        p0 = bi * PPB;
    }

    // ---------------- per-pixel setup: threads 0..63 ----------------------
    if (tid < PPB) {
        const int p = p0 + tid;

        const float rx = rot_p[0], ry = rot_p[1], rz = rot_p[2];
        const float th2 = rx*rx + ry*ry + rz*rz;
        const float th  = sqrtf(th2 + 1e-30f);
        const float a   = (th2 < 1e-12f) ? (1.0f - th2 * (1.0f/6.0f))  : (sinf(th) / th);
        const float b   = (th2 < 1e-12f) ? (0.5f - th2 * (1.0f/24.0f)) : ((1.0f - cosf(th)) / th2);
        float Rm[3][3];
        Rm[0][0] = 1.0f + b * (-(ry*ry + rz*rz));
        Rm[0][1] = a * (-rz) + b * (rx*ry);
        Rm[0][2] = a * ( ry) + b * (rx*rz);
        Rm[1][0] = a * ( rz) + b * (rx*ry);
        Rm[1][1] = 1.0f + b * (-(rx*rx + rz*rz));
        Rm[1][2] = a * (-rx) + b * (ry*rz);
        Rm[2][0] = a * (-ry) + b * (rx*rz);
        Rm[2][1] = a * ( rx) + b * (ry*rz);
        Rm[2][2] = 1.0f + b * (-(rx*rx + ry*ry));
        const float tv[3] = { xyz_p[0], xyz_p[1], xyz_p[2] };
        const float* M = rt_inv;
        float Rw[3][3], tw[3];
        #pragma unroll
        for (int i = 0; i < 3; ++i) {
            #pragma unroll
            for (int j = 0; j < 4; ++j) {
                float s = Rm[i][0]*M[0*4+j] + Rm[i][1]*M[1*4+j]
                        + Rm[i][2]*M[2*4+j] + tv[i]*M[3*4+j];
                if (j < 3) Rw[i][j] = s; else tw[i] = s;
            }
        }
        const float c = 0.5f * (float)(D - 1);
        if (tid == 0) { s_q[0] = tw[0] + c; s_q[1] = tw[1] + c; s_q[2] = tw[2] + c; }

        int   ilo = 0, ihi = -1;
        float rayx = 0.f, rayy = 0.f, rayz = 0.f, seglen = 0.f;
        if (p < npix) {
            const int h = p / W;
            const int w = p - h * W;
            const float sdd = sdd_p[0];
            const float u = (float)w + 0.5f;
            const float v = (float)h + 0.5f;
            const float cx = (k_inv[0]*u + k_inv[1]*v + k_inv[2]) * sdd;
            const float cy = (k_inv[3]*u + k_inv[4]*v + k_inv[5]) * sdd;
            const float cz = (k_inv[6]*u + k_inv[7]*v + k_inv[8]) * sdd;
            const float tgx = Rw[0][0]*cx + Rw[0][1]*cy + Rw[0][2]*cz + tw[0];
            const float tgy = Rw[1][0]*cx + Rw[1][1]*cy + Rw[1][2]*cz + tw[1];
            const float tgz = Rw[2][0]*cx + Rw[2][1]*cy + Rw[2][2]*cz + tw[2];
            rayx = tgx - tw[0];
            rayy = tgy - tw[1];
            rayz = tgz - tw[2];
            seglen = sqrtf(rayx*rayx + rayy*rayy + rayz*rayz) / fn;

            const float qs[3] = { tw[0] + c, tw[1] + c, tw[2] + c };
            const float rs[3] = { rayx, rayy, rayz };
            float alo = -1e30f, ahi = 1e30f;
            bool empty = false;
            #pragma unroll
            for (int ax = 0; ax < 3; ++ax) {
                const float q = qs[ax], r = rs[ax];
                if (fabsf(r) < 1e-20f) {
                    if (q < 0.0f || q > dimf) empty = true;
                } else {
                    const float t0 = (0.0f - q) / r;
                    const float t1 = (dimf - q) / r;
                    alo = fmaxf(alo, fminf(t0, t1));
                    ahi = fminf(ahi, fmaxf(t0, t1));
                }
            }
            if (!empty && alo <= ahi) {
                ilo = (int)ceilf (alo * fn - 0.5f) - 1;   // widen by 1;
                ihi = (int)floorf(ahi * fn - 0.5f) + 1;   // exact check below
                ilo = max(ilo, 0);
                ihi = min(ihi, n - 1);
            }
        }
        s_rayx[tid] = rayx;  s_rayy[tid] = rayy;  s_rayz[tid] = rayz;
        s_seglen[tid] = seglen;
        s_ilo[tid] = ilo;    s_ihi[tid] = ihi;
    }
    __syncthreads();

    // ------------- main: wave = 64 u-pixels, contiguous step range --------
    const int slot  = tid & (PPB - 1);
    const int chunk = tid >> 6;          // wave id within block

    const float rayx = s_rayx[slot], rayy = s_rayy[slot], rayz = s_rayz[slot];
    const float qx = s_q[0], qy = s_q[1], qz = s_q[2];
    const int ilo = s_ilo[slot], ihi = s_ihi[slot];
    const int count = ihi - ilo + 1;

    float acc = 0.0f;
    if (count > 0) {
        const int len = (count + CHUNKS - 1) / CHUNKS;
        const int sc  = ilo + chunk * len;
        const int ec  = min(sc + len - 1, ihi);
        const float inv_n = 1.0f / fn;

        for (int i = sc; i <= ec; ++i) {
            const float alpha = ((float)i + 0.5f) * inv_n;
            const float px = fmaf(alpha, rayx, qx);
            const float py = fmaf(alpha, rayy, qy);
            const float pz = fmaf(alpha, rayz, qz);
            const bool inside = (px >= 0.0f) & (px <= dimf)
                              & (py >= 0.0f) & (py <= dimf)
                              & (pz >= 0.0f) & (pz <= dimf);
            if (!inside) continue;
            const float fxf = floorf(px), fyf = floorf(py), fzf = floorf(pz);
            const float fx = px - fxf, fy = py - fyf, fz = pz - fzf;
            const int x0 = min(max((int)fxf, 0), D - 2);
            const int y0 = min(max((int)fyf, 0), D - 2);
            const int z0 = min(max((int)fzf, 0), D - 2);
            const float* b000 = vol + ((size_t)x0 * DD + (size_t)y0 * D + z0);
            // z-pair merged loads: (z0, z0+1) adjacent in memory
            const f32x2 vA = *(const f32x2*)(b000);            // c000 c001
            const f32x2 vB = *(const f32x2*)(b000 + D);        // c010 c011
            const f32x2 vC = *(const f32x2*)(b000 + DD);       // c100 c101
            const f32x2 vD = *(const f32x2*)(b000 + DD + D);   // c110 c111
            const float c00 = vA.x * (1.0f - fz) + vA.y * fz;
            const float c01 = vB.x * (1.0f - fz) + vB.y * fz;
            const float c10 = vC.x * (1.0f - fz) + vC.y * fz;
            const float c11 = vD.x * (1.0f - fz) + vD.y * fz;
            const float c0  = c00 * (1.0f - fy) + c01 * fy;
            const float c1  = c10 * (1.0f - fy) + c11 * fy;
            acc += c0 * (1.0f - fx) + c1 * fx;
        }
    }

    s_red[chunk][slot] = acc;
    __syncthreads();

    if (tid < PPB) {
        float s = 0.0f;
        #pragma unroll
        for (int k = 0; k < CHUNKS; ++k) s += s_red[k][tid];
        const int p = p0 + tid;
        if (p < npix) out[p] = s * s_seglen[tid];
    }
}

extern "C" void kernel_launch(void* const* d_in, const int* in_sizes, int n_in,
                              void* d_out, int out_size, void* d_ws, size_t ws_size,
                              hipStream_t stream) {
    const float* vol    = (const float*)d_in[0];
    const float* rt_inv = (const float*)d_in[1];
    const float* k_inv  = (const float*)d_in[2];
    const float* sdd    = (const float*)d_in[3];
    const float* rot    = (const float*)d_in[4];
    const float* xyz    = (const float*)d_in[5];
    const int*   width  = (const int*)d_in[7];
    const int*   nsteps = (const int*)d_in[8];
    float* out = (float*)d_out;

    const int npix = out_size;                       // H*W
    const int D    = (int)lround(cbrt((double)in_sizes[0]));

    const int blocks = (npix + PPB - 1) / PPB;
    if (D == 256) {
        drr_swz_kernel<256><<<blocks, BLOCK, 0, stream>>>(
            vol, rt_inv, k_inv, sdd, rot, xyz, width, nsteps, out, npix, D);
    } else {
        drr_swz_kernel<0><<<blocks, BLOCK, 0, stream>>>(
            vol, rt_inv, k_inv, sdd, rot, xyz, width, nsteps, out, npix, D);
    }
}

// Round 5
// 22.359 us; speedup vs baseline: 1.4276x; 1.3600x over previous
//
#include <hip/hip_runtime.h>
#include <math.h>

// DRR ray-caster, round 5 = round-1 kernel (22.3 us, best so far) with
// EXACTLY ONE change: the 8 scalar corner gathers are merged into 4 f32x2
// gathers over z-pairs (z0,z0+1 are adjacent in memory and share a 64B
// line ~94% of the time). Line-iteration model: 272 -> ~140 line touches
// per wave-iteration => predicts ~12-15 us.
// f32x2 load semantics validated on HW in round 4 (passed, absmax 1.0).

#define BLOCK  256
#define CHUNKS 8
#define PPB    (BLOCK / CHUNKS)   // 32 pixels per block

typedef float f32x2 __attribute__((ext_vector_type(2), aligned(4)));

__global__ __launch_bounds__(BLOCK) void drr_kernel(
    const float* __restrict__ vol,
    const float* __restrict__ rt_inv,
    const float* __restrict__ k_inv,
    const float* __restrict__ sdd_p,
    const float* __restrict__ rot_p,
    const float* __restrict__ xyz_p,
    const int*   __restrict__ width_p,
    const int*   __restrict__ nsteps_p,
    float*       __restrict__ out,
    const int npix, const int D)
{
    const int tid   = (int)threadIdx.x;
    const int slot  = tid & (PPB - 1);   // pixel slot within block
    const int chunk = tid / PPB;         // step-chunk id [0, CHUNKS)
    const int p     = (int)blockIdx.x * PPB + slot;

    float acc    = 0.0f;
    float seglen = 0.0f;

    if (p < npix) {
        const int W = *width_p;
        const int n = *nsteps_p;
        const int h = p / W;
        const int w = p - h * W;

        // ---- pose: Rodrigues(_rot), then T = P @ rt_inv ----
        const float rx = rot_p[0], ry = rot_p[1], rz = rot_p[2];
        const float th2 = rx*rx + ry*ry + rz*rz;
        const float th  = sqrtf(th2 + 1e-30f);
        const float a   = (th2 < 1e-12f) ? (1.0f - th2 * (1.0f/6.0f))  : (sinf(th) / th);
        const float b   = (th2 < 1e-12f) ? (0.5f - th2 * (1.0f/24.0f)) : ((1.0f - cosf(th)) / th2);
        float Rm[3][3];
        Rm[0][0] = 1.0f + b * (-(ry*ry + rz*rz));
        Rm[0][1] = a * (-rz) + b * (rx*ry);
        Rm[0][2] = a * ( ry) + b * (rx*rz);
        Rm[1][0] = a * ( rz) + b * (rx*ry);
        Rm[1][1] = 1.0f + b * (-(rx*rx + rz*rz));
        Rm[1][2] = a * (-rx) + b * (ry*rz);
        Rm[2][0] = a * (-ry) + b * (rx*rz);
        Rm[2][1] = a * ( rx) + b * (ry*rz);
        Rm[2][2] = 1.0f + b * (-(rx*rx + ry*ry));
        const float tv[3] = { xyz_p[0], xyz_p[1], xyz_p[2] };
        const float* M = rt_inv;
        float Rw[3][3], tw[3];
        #pragma unroll
        for (int i = 0; i < 3; ++i) {
            #pragma unroll
            for (int j = 0; j < 4; ++j) {
                float s = Rm[i][0]*M[0*4+j] + Rm[i][1]*M[1*4+j]
                        + Rm[i][2]*M[2*4+j] + tv[i]*M[3*4+j];
                if (j < 3) Rw[i][j] = s; else tw[i] = s;
            }
        }

        const float sdd = sdd_p[0];
        const float u = (float)w + 0.5f;
        const float v = (float)h + 0.5f;
        // cam = (k_inv @ [u,v,1]) * sdd
        const float cx = (k_inv[0]*u + k_inv[1]*v + k_inv[2]) * sdd;
        const float cy = (k_inv[3]*u + k_inv[4]*v + k_inv[5]) * sdd;
        const float cz = (k_inv[6]*u + k_inv[7]*v + k_inv[8]) * sdd;
        // tgt = Rw@cam + tw ; src = tw ; ray = tgt - src (keep reference order)
        const float tgx = Rw[0][0]*cx + Rw[0][1]*cy + Rw[0][2]*cz + tw[0];
        const float tgy = Rw[1][0]*cx + Rw[1][1]*cy + Rw[1][2]*cz + tw[1];
        const float tgz = Rw[2][0]*cx + Rw[2][1]*cy + Rw[2][2]*cz + tw[2];
        const float rayx = tgx - tw[0];
        const float rayy = tgy - tw[1];
        const float rayz = tgz - tw[2];
        const float fn = (float)n;
        seglen = sqrtf(rayx*rayx + rayy*rayy + rayz*rayz) / fn;

        const float c    = 0.5f * (float)(D - 1);   // 127.5
        const float dimf = (float)(D - 1);          // 255.0
        // idx_axis(alpha) = (tw + alpha*ray) + c  -> q + alpha*ray
        const float qx = tw[0] + c, qy = tw[1] + c, qz = tw[2] + c;

        // analytic alpha range where all axes are inside [0, dimf]
        float alo = -1e30f, ahi = 1e30f;
        bool empty = false;
        {
            const float qs[3] = { qx, qy, qz };
            const float rs[3] = { rayx, rayy, rayz };
            #pragma unroll
            for (int ax = 0; ax < 3; ++ax) {
                const float q = qs[ax], r = rs[ax];
                if (fabsf(r) < 1e-20f) {
                    if (q < 0.0f || q > dimf) empty = true;
                } else {
                    const float t0 = (0.0f - q) / r;
                    const float t1 = (dimf - q) / r;
                    alo = fmaxf(alo, fminf(t0, t1));
                    ahi = fminf(ahi, fmaxf(t0, t1));
                }
            }
        }

        if (!empty && alo <= ahi) {
            // step range: alpha_i = (i+0.5)/n in [alo, ahi]; widen by 1 for
            // float safety, keep the exact per-step inside check below.
            int ilo = (int)ceilf (alo * fn - 0.5f) - 1;
            int ihi = (int)floorf(ahi * fn - 0.5f) + 1;
            ilo = max(ilo, 0);
            ihi = min(ihi, n - 1);
            // first step index >= ilo congruent to this thread's chunk
            int start = ilo + ((chunk - ilo) % CHUNKS + CHUNKS) % CHUNKS;

            const float inv_n = 1.0f / fn;
            const int DD = D * D;
            for (int i = start; i <= ihi; i += CHUNKS) {
                const float alpha = ((float)i + 0.5f) * inv_n;
                const float px = fmaf(alpha, rayx, qx);
                const float py = fmaf(alpha, rayy, qy);
                const float pz = fmaf(alpha, rayz, qz);
                const bool inside = (px >= 0.0f) & (px <= dimf)
                                  & (py >= 0.0f) & (py <= dimf)
                                  & (pz >= 0.0f) & (pz <= dimf);
                if (!inside) continue;
                const float fxf = floorf(px), fyf = floorf(py), fzf = floorf(pz);
                const float fx = px - fxf, fy = py - fyf, fz = pz - fzf;
                int x0 = min(max((int)fxf, 0), D - 2);
                int y0 = min(max((int)fyf, 0), D - 2);
                int z0 = min(max((int)fzf, 0), D - 2);
                const float* b000 = vol + (size_t)x0 * DD + (size_t)y0 * D + z0;
                // THE one change vs round 1: z-pair merged gathers (8 -> 4).
                const f32x2 vA = *(const f32x2*)(b000);            // c000 c001
                const f32x2 vB = *(const f32x2*)(b000 + D);        // c010 c011
                const f32x2 vC = *(const f32x2*)(b000 + DD);       // c100 c101
                const f32x2 vD = *(const f32x2*)(b000 + DD + D);   // c110 c111
                const float c00 = vA.x * (1.0f - fz) + vA.y * fz;
                const float c01 = vB.x * (1.0f - fz) + vB.y * fz;
                const float c10 = vC.x * (1.0f - fz) + vC.y * fz;
                const float c11 = vD.x * (1.0f - fz) + vD.y * fz;
                const float c0  = c00 * (1.0f - fy) + c01 * fy;
                const float c1  = c10 * (1.0f - fy) + c11 * fy;
                acc += c0 * (1.0f - fx) + c1 * fx;
            }
        }
    }

    // reduce CHUNKS partials per pixel
    __shared__ float red[BLOCK];
    red[tid] = acc;
    __syncthreads();
    if (tid < PPB) {
        float s = 0.0f;
        #pragma unroll
        for (int k = 0; k < CHUNKS; ++k) s += red[tid + k * PPB];
        if (p < npix) out[p] = s * seglen;
    }
}

extern "C" void kernel_launch(void* const* d_in, const int* in_sizes, int n_in,
                              void* d_out, int out_size, void* d_ws, size_t ws_size,
                              hipStream_t stream) {
    const float* vol    = (const float*)d_in[0];
    const float* rt_inv = (const float*)d_in[1];
    const float* k_inv  = (const float*)d_in[2];
    const float* sdd    = (const float*)d_in[3];
    const float* rot    = (const float*)d_in[4];
    const float* xyz    = (const float*)d_in[5];
    const int*   width  = (const int*)d_in[7];
    const int*   nsteps = (const int*)d_in[8];
    float* out = (float*)d_out;

    const int npix = out_size;                       // H*W
    const int D    = (int)lround(cbrt((double)in_sizes[0]));

    const int blocks = (npix + PPB - 1) / PPB;
    drr_kernel<<<blocks, BLOCK, 0, stream>>>(
        vol, rt_inv, k_inv, sdd, rot, xyz, width, nsteps, out, npix, D);
}